// Round 1
// baseline (4705.099 us; speedup 1.0000x reference)
//
#include <hip/hip_runtime.h>
#include <math.h>

// Problem constants (fixed by the reference): K=32 neighbors, D=128, F=256.
#define KN 32
#define DD 128
#define FF 256

__device__ __forceinline__ float gelu_f(float x) {
    // exact (erf) GELU, matches jax.nn.gelu(approximate=False)
    return 0.5f * x * (1.0f + erff(x * 0.70710678118654752440f));
}

__launch_bounds__(256, 3)
__global__ void ff_fused_kernel(
    const float* __restrict__ xyt_q,
    const float* __restrict__ obs_coords,
    const float* __restrict__ obs_vals,
    const int*   __restrict__ nb_idx,
    const float* __restrict__ log_gammas,
    const float* __restrict__ w_in,   // [128,4]
    const float* __restrict__ b_in,   // [128]
    const float* __restrict__ ln1_g,  // [128]
    const float* __restrict__ ln1_b,  // [128]
    const float* __restrict__ w1,     // [256,128]
    const float* __restrict__ b1,     // [256]
    const float* __restrict__ w2,     // [128,256]
    const float* __restrict__ b2,     // [128]
    const float* __restrict__ hln_g,  // [256]
    const float* __restrict__ hln_b,  // [256]
    const float* __restrict__ hw1,    // [256,256]
    const float* __restrict__ hb1,    // [256]
    const float* __restrict__ hw2,    // [1,256]
    const float* __restrict__ hb2,    // [1]
    float* __restrict__ out)          // [Q]
{
    __shared__ __align__(16) float s_tok[KN][4];          // tokens [32,4]
    __shared__ __align__(16) float s_h[KN][DD + 4];       // h / h2 [32,132]
    __shared__ __align__(16) float s_x[KN][FF + 4];       // x      [32,260]
    __shared__ __align__(16) float s_pool[2 * DD];        // pooled [256]
    __shared__ __align__(16) float s_pln[2 * DD];         // LN(pooled) [256]
    __shared__ float s_mu, s_sigma;
    __shared__ float s_red[4];

    const int q = blockIdx.x;
    const int t = threadIdx.x;
    const int wave = t >> 6;
    const int lane = t & 63;

    // ---------------- Phase 0: gather neighbors, build tokens, mu/sigma ----
    if (t < KN) {
        int idx = nb_idx[q * KN + t];
        float v = obs_vals[idx];
        #pragma unroll
        for (int j = 0; j < 3; j++) {
            s_tok[t][j] = (obs_coords[idx * 3 + j] - xyt_q[q * 3 + j]) * expf(log_gammas[j]);
        }
        // reduce sum / sumsq across 32 lanes (all in wave 0)
        float s = v, ss = v * v;
        #pragma unroll
        for (int m = 1; m < 32; m <<= 1) {
            s  += __shfl_xor(s, m);
            ss += __shfl_xor(ss, m);
        }
        float mu  = s * (1.0f / KN);
        float var = (ss - (float)KN * mu * mu) * (1.0f / (KN - 1));  // ddof=1
        var = fmaxf(var, 0.0f);
        float sigma = fmaxf(sqrtf(var), 1e-3f);                      // clip min 1e-3
        if (t == 0) { s_mu = mu; s_sigma = sigma; }
        s_tok[t][3] = (v - mu) / sigma;
    }
    __syncthreads();

    // ---------------- Phase 1: h = gelu(tokens @ w_in^T + b_in)  [32,128] --
    #pragma unroll
    for (int i = 0; i < 16; i++) {
        int kd = t + 256 * i;          // 0..4095
        int k = kd >> 7, d = kd & 127;
        float4 w  = ((const float4*)w_in)[d];       // w_in[d][0..3]
        float4 tk = *(const float4*)(&s_tok[k][0]); // broadcast within wave
        float a = fmaf(w.x, tk.x, fmaf(w.y, tk.y, fmaf(w.z, tk.z, fmaf(w.w, tk.w, b_in[d]))));
        s_h[k][d] = gelu_f(a);
    }
    __syncthreads();

    // ---------------- Phase 2: LayerNorm over D per token (in-place) -------
    {
        float g0 = ln1_g[lane], g1 = ln1_g[lane + 64];
        float c0 = ln1_b[lane], c1 = ln1_b[lane + 64];
        #pragma unroll
        for (int i = 0; i < 8; i++) {
            int k = wave * 8 + i;
            float v0 = s_h[k][lane], v1 = s_h[k][lane + 64];
            float s = v0 + v1, ss = v0 * v0 + v1 * v1;
            #pragma unroll
            for (int m = 1; m < 64; m <<= 1) {
                s  += __shfl_xor(s, m);
                ss += __shfl_xor(ss, m);
            }
            float mean = s * (1.0f / DD);
            float var  = ss * (1.0f / DD) - mean * mean;  // ddof=0
            float rstd = rsqrtf(fmaxf(var, 0.0f) + 1e-5f);
            s_h[k][lane]      = (v0 - mean) * rstd * g0 + c0;
            s_h[k][lane + 64] = (v1 - mean) * rstd * g1 + c1;
        }
    }
    __syncthreads();

    // ---------------- Phase 3: x = gelu(h_ln @ w1^T + b1)  [32,256] --------
    {
        const int f0 = (t & 63) * 4;   // 0..252
        const int k0 = (t >> 6) * 8;   // 0,8,16,24
        float acc[4][8];
        #pragma unroll
        for (int i = 0; i < 4; i++) {
            float bi = b1[f0 + i];
            #pragma unroll
            for (int j = 0; j < 8; j++) acc[i][j] = bi;
        }
        for (int d0 = 0; d0 < DD; d0 += 8) {
            float w[4][8];
            #pragma unroll
            for (int i = 0; i < 4; i++) {
                float4 wa = *(const float4*)&w1[(f0 + i) * DD + d0];
                float4 wb = *(const float4*)&w1[(f0 + i) * DD + d0 + 4];
                w[i][0] = wa.x; w[i][1] = wa.y; w[i][2] = wa.z; w[i][3] = wa.w;
                w[i][4] = wb.x; w[i][5] = wb.y; w[i][6] = wb.z; w[i][7] = wb.w;
            }
            #pragma unroll
            for (int dd = 0; dd < 8; dd += 4) {
                #pragma unroll
                for (int j = 0; j < 8; j++) {
                    float4 hv = *(const float4*)&s_h[k0 + j][d0 + dd];  // broadcast in wave
                    #pragma unroll
                    for (int i = 0; i < 4; i++) {
                        acc[i][j] = fmaf(w[i][dd + 0], hv.x, acc[i][j]);
                        acc[i][j] = fmaf(w[i][dd + 1], hv.y, acc[i][j]);
                        acc[i][j] = fmaf(w[i][dd + 2], hv.z, acc[i][j]);
                        acc[i][j] = fmaf(w[i][dd + 3], hv.w, acc[i][j]);
                    }
                }
            }
        }
        #pragma unroll
        for (int j = 0; j < 8; j++) {
            float4 o;
            o.x = gelu_f(acc[0][j]); o.y = gelu_f(acc[1][j]);
            o.z = gelu_f(acc[2][j]); o.w = gelu_f(acc[3][j]);
            *(float4*)&s_x[k0 + j][f0] = o;
        }
    }
    __syncthreads();

    // ---------------- Phase 4: h2 = gelu(x @ w2^T + b2)  [32,128] ----------
    {
        const int d0 = (t & 63) * 2;   // 0..126
        const int k0 = (t >> 6) * 8;
        float acc[2][8];
        #pragma unroll
        for (int i = 0; i < 2; i++) {
            float bi = b2[d0 + i];
            #pragma unroll
            for (int j = 0; j < 8; j++) acc[i][j] = bi;
        }
        for (int c0 = 0; c0 < FF; c0 += 8) {
            float w[2][8];
            #pragma unroll
            for (int i = 0; i < 2; i++) {
                float4 wa = *(const float4*)&w2[(d0 + i) * FF + c0];
                float4 wb = *(const float4*)&w2[(d0 + i) * FF + c0 + 4];
                w[i][0] = wa.x; w[i][1] = wa.y; w[i][2] = wa.z; w[i][3] = wa.w;
                w[i][4] = wb.x; w[i][5] = wb.y; w[i][6] = wb.z; w[i][7] = wb.w;
            }
            #pragma unroll
            for (int cc = 0; cc < 8; cc += 4) {
                #pragma unroll
                for (int j = 0; j < 8; j++) {
                    float4 xv = *(const float4*)&s_x[k0 + j][c0 + cc];  // broadcast in wave
                    #pragma unroll
                    for (int i = 0; i < 2; i++) {
                        acc[i][j] = fmaf(w[i][cc + 0], xv.x, acc[i][j]);
                        acc[i][j] = fmaf(w[i][cc + 1], xv.y, acc[i][j]);
                        acc[i][j] = fmaf(w[i][cc + 2], xv.z, acc[i][j]);
                        acc[i][j] = fmaf(w[i][cc + 3], xv.w, acc[i][j]);
                    }
                }
            }
        }
        __syncthreads();   // make sure phase-3 readers of s_h are done before overwrite
        #pragma unroll
        for (int j = 0; j < 8; j++) {
            float2 o;
            o.x = gelu_f(acc[0][j]); o.y = gelu_f(acc[1][j]);
            *(float2*)&s_h[k0 + j][d0] = o;
        }
    }
    __syncthreads();

    // ---------------- Phase 5: pool mean/max over K ------------------------
    if (t < DD) {
        float s = 0.0f, mx = -INFINITY;
        #pragma unroll
        for (int k = 0; k < KN; k++) {
            float v = s_h[k][t];
            s += v; mx = fmaxf(mx, v);
        }
        s_pool[t] = s * (1.0f / KN);
        s_pool[DD + t] = mx;
    }
    __syncthreads();

    // ---------------- Phase 6: head LayerNorm over 256 (wave 0) ------------
    if (t < 64) {
        float v0 = s_pool[t], v1 = s_pool[t + 64], v2 = s_pool[t + 128], v3 = s_pool[t + 192];
        float s = v0 + v1 + v2 + v3;
        float ss = v0 * v0 + v1 * v1 + v2 * v2 + v3 * v3;
        #pragma unroll
        for (int m = 1; m < 64; m <<= 1) {
            s  += __shfl_xor(s, m);
            ss += __shfl_xor(ss, m);
        }
        float mean = s * (1.0f / (2 * DD));
        float var  = ss * (1.0f / (2 * DD)) - mean * mean;
        float rstd = rsqrtf(fmaxf(var, 0.0f) + 1e-5f);
        s_pln[t]       = (v0 - mean) * rstd * hln_g[t]       + hln_b[t];
        s_pln[t + 64]  = (v1 - mean) * rstd * hln_g[t + 64]  + hln_b[t + 64];
        s_pln[t + 128] = (v2 - mean) * rstd * hln_g[t + 128] + hln_b[t + 128];
        s_pln[t + 192] = (v3 - mean) * rstd * hln_g[t + 192] + hln_b[t + 192];
    }
    __syncthreads();

    // ---------------- Phase 7: head MLP + output ---------------------------
    {
        float acc = hb1[t];
        const float4* hr = (const float4*)&hw1[t * (2 * DD)];
        #pragma unroll 8
        for (int c = 0; c < 64; c++) {
            float4 w = hr[c];
            float4 p = *(const float4*)&s_pln[c * 4];   // broadcast in wave
            acc = fmaf(w.x, p.x, fmaf(w.y, p.y, fmaf(w.z, p.z, fmaf(w.w, p.w, acc))));
        }
        float contrib = gelu_f(acc) * hw2[t];
        #pragma unroll
        for (int m = 1; m < 64; m <<= 1) contrib += __shfl_xor(contrib, m);
        if (lane == 0) s_red[wave] = contrib;
    }
    __syncthreads();
    if (t == 0) {
        float u = s_red[0] + s_red[1] + s_red[2] + s_red[3] + hb2[0];
        out[q] = u * s_sigma + s_mu;
    }
}

extern "C" void kernel_launch(void* const* d_in, const int* in_sizes, int n_in,
                              void* d_out, int out_size, void* d_ws, size_t ws_size,
                              hipStream_t stream)
{
    const float* xyt_q      = (const float*)d_in[0];
    const float* obs_coords = (const float*)d_in[1];
    const float* obs_vals   = (const float*)d_in[2];
    const int*   nb_idx     = (const int*)d_in[3];
    const float* log_gammas = (const float*)d_in[4];
    const float* w_in  = (const float*)d_in[5];
    const float* b_in  = (const float*)d_in[6];
    const float* ln1_g = (const float*)d_in[7];
    const float* ln1_b = (const float*)d_in[8];
    const float* w1    = (const float*)d_in[9];
    const float* b1    = (const float*)d_in[10];
    const float* w2    = (const float*)d_in[11];
    const float* b2    = (const float*)d_in[12];
    const float* hln_g = (const float*)d_in[13];
    const float* hln_b = (const float*)d_in[14];
    const float* hw1   = (const float*)d_in[15];
    const float* hb1   = (const float*)d_in[16];
    const float* hw2   = (const float*)d_in[17];
    const float* hb2   = (const float*)d_in[18];
    float* out = (float*)d_out;

    const int Q = in_sizes[0] / 3;   // 32768

    ff_fused_kernel<<<Q, 256, 0, stream>>>(
        xyt_q, obs_coords, obs_vals, nb_idx, log_gammas,
        w_in, b_in, ln1_g, ln1_b, w1, b1, w2, b2,
        hln_g, hln_b, hw1, hb1, hw2, hb2, out);
}

// Round 2
// 855.221 us; speedup vs baseline: 5.5016x; 5.5016x over previous
//
#include <hip/hip_runtime.h>
#include <math.h>

// FieldFormer fused kernel, round 2: bf16 MFMA for the two token GEMMs.
// K=32 neighbors, D=128, F=256, QB=2 queries/block -> M=64 token rows.
#define KN 32
#define DD 128
#define FF 256
#define QB 2
#define MROWS (QB * KN)      // 64
#define HP 136               // s_hA pitch (ushort), 128+8 pad -> bank-conflict free
#define XP 264               // s_x  pitch (ushort), 256+8 pad

typedef __attribute__((ext_vector_type(8))) short bf16x8;
typedef __attribute__((ext_vector_type(4))) float f32x4;

__device__ __forceinline__ unsigned short f2bf(float x) {
    union { float f; unsigned u; } c; c.f = x;
    unsigned r = c.u + 0x7fffu + ((c.u >> 16) & 1u);   // RNE
    return (unsigned short)(r >> 16);
}
__device__ __forceinline__ float bf2f(unsigned short h) {
    union { unsigned u; float f; } c; c.u = ((unsigned)h) << 16;
    return c.f;
}
__device__ __forceinline__ float gelu_f(float x) {
    return 0.5f * x * (1.0f + erff(x * 0.70710678118654752440f));
}

// Prep: w1 [256,128] -> bf16, w2 [128,256] -> bf16, hw1 [256,256] -> transposed
// packed pairs hw1p[c2*256+f] = (bf16(hw1[f][2c2]), bf16(hw1[f][2c2+1])).
__global__ void prep_kernel(const float* __restrict__ w1,
                            const float* __restrict__ w2,
                            const float* __restrict__ hw1,
                            unsigned short* __restrict__ w1b,
                            unsigned short* __restrict__ w2b,
                            unsigned* __restrict__ hw1p) {
    int i = blockIdx.x * 256 + threadIdx.x;   // 0..32767
    w1b[i] = f2bf(w1[i]);
    w2b[i] = f2bf(w2[i]);
    int c2 = i >> 8, f = i & 255;
    unsigned lo = f2bf(hw1[f * 256 + 2 * c2]);
    unsigned hi = f2bf(hw1[f * 256 + 2 * c2 + 1]);
    hw1p[i] = lo | (hi << 16);
}

__launch_bounds__(256, 3)
__global__ void ff_mfma_kernel(
    const float* __restrict__ xyt_q,
    const float* __restrict__ obs_coords,
    const float* __restrict__ obs_vals,
    const int*   __restrict__ nb_idx,
    const float* __restrict__ log_gammas,
    const float* __restrict__ w_in,   // [128,4]
    const float* __restrict__ b_in,
    const float* __restrict__ ln1_g,
    const float* __restrict__ ln1_b,
    const unsigned short* __restrict__ w1b,  // [256,128] bf16
    const float* __restrict__ b1,
    const unsigned short* __restrict__ w2b,  // [128,256] bf16
    const float* __restrict__ b2,
    const float* __restrict__ hln_g,
    const float* __restrict__ hln_b,
    const unsigned* __restrict__ hw1p,       // [128,256] packed bf16 pairs
    const float* __restrict__ hb1,
    const float* __restrict__ hw2,
    const float* __restrict__ hb2,
    float* __restrict__ out)
{
    __shared__ __align__(16) unsigned short s_hA[MROWS * HP];  // 17408 B: h_ln, then h2
    __shared__ __align__(16) unsigned char  s_big[33792];      // aliased: hf fp32 / x bf16 / pool+pln
    __shared__ __align__(16) float s_tokf[MROWS][4];
    __shared__ float s_mu[QB], s_sig[QB];
    __shared__ float s_red[4][QB];

    const int t    = threadIdx.x;
    const int lane = t & 63;
    const int wv   = t >> 6;
    const int m16  = lane & 15;
    const int quad = lane >> 4;
    const int q0   = blockIdx.x * QB;

    float*          hf     = (float*)s_big;            // [64][132] fp32 (phase 1-2)
    unsigned short* s_x    = (unsigned short*)s_big;   // [64][264] bf16 (phase 3-4)
    float*          s_pool = (float*)s_big;            // [2][256]  (phase 5-6)
    float*          s_pln  = (float*)(s_big + 4096);   // [2][256]

    // ---- Phase 0: gather neighbors, tokens, mu/sigma (ddof=1, clip 1e-3) ----
    if (t < MROWS) {
        int qi = t >> 5, j = t & 31;
        int q = q0 + qi;
        int idx = nb_idx[q * KN + j];
        float v = obs_vals[idx];
        float g0 = expf(log_gammas[0]), g1 = expf(log_gammas[1]), g2 = expf(log_gammas[2]);
        s_tokf[t][0] = (obs_coords[idx * 3 + 0] - xyt_q[q * 3 + 0]) * g0;
        s_tokf[t][1] = (obs_coords[idx * 3 + 1] - xyt_q[q * 3 + 1]) * g1;
        s_tokf[t][2] = (obs_coords[idx * 3 + 2] - xyt_q[q * 3 + 2]) * g2;
        float s = v, ss = v * v;
        #pragma unroll
        for (int m = 1; m < 32; m <<= 1) {    // groups of 32 lanes = one query
            s  += __shfl_xor(s, m);
            ss += __shfl_xor(ss, m);
        }
        float mu  = s * (1.0f / KN);
        float var = (ss - (float)KN * mu * mu) * (1.0f / (KN - 1));
        float sig = fmaxf(sqrtf(fmaxf(var, 0.0f)), 1e-3f);
        if (j == 0) { s_mu[qi] = mu; s_sig[qi] = sig; }
        s_tokf[t][3] = (v - mu) / sig;
    }
    __syncthreads();

    // ---- Phase 1: hf = gelu(tok @ w_in^T + b_in)  [64,128] fp32 ----
    #pragma unroll
    for (int i = 0; i < 32; i++) {
        int idx = t + 256 * i;         // 0..8191
        int tok = idx >> 7, d = idx & 127;
        float4 w  = ((const float4*)w_in)[d];
        float4 tk = *(const float4*)&s_tokf[tok][0];
        float a = fmaf(w.x, tk.x, fmaf(w.y, tk.y, fmaf(w.z, tk.z, fmaf(w.w, tk.w, b_in[d]))));
        hf[tok * 132 + d] = gelu_f(a);
    }
    __syncthreads();

    // ---- Phase 2: LN over 128 (fp32) -> bf16 s_hA ----
    {
        float g0 = ln1_g[lane], g1 = ln1_g[lane + 64];
        float c0 = ln1_b[lane], c1 = ln1_b[lane + 64];
        #pragma unroll
        for (int i = 0; i < 16; i++) {
            int tok = wv * 16 + i;
            float v0 = hf[tok * 132 + lane], v1 = hf[tok * 132 + 64 + lane];
            float s = v0 + v1, ss = v0 * v0 + v1 * v1;
            #pragma unroll
            for (int m = 1; m < 64; m <<= 1) {
                s  += __shfl_xor(s, m);
                ss += __shfl_xor(ss, m);
            }
            float mean = s * (1.0f / DD);
            float var  = ss * (1.0f / DD) - mean * mean;
            float rstd = rsqrtf(fmaxf(var, 0.0f) + 1e-5f);
            s_hA[tok * HP + lane]      = f2bf((v0 - mean) * rstd * g0 + c0);
            s_hA[tok * HP + 64 + lane] = f2bf((v1 - mean) * rstd * g1 + c1);
        }
    }
    __syncthreads();

    // ---- Phase 3: MFMA GEMM1  x = gelu(hln @ w1^T + b1), wave strip cols [wv*64, wv*64+64) ----
    {
        bf16x8 B[4][4];
        #pragma unroll
        for (int ct = 0; ct < 4; ct++)
            #pragma unroll
            for (int kk = 0; kk < 4; kk++)
                B[ct][kk] = *(const bf16x8*)&w1b[(wv * 64 + ct * 16 + m16) * 128 + kk * 32 + quad * 8];
        #pragma unroll
        for (int rt = 0; rt < 4; rt++) {
            bf16x8 A[4];
            #pragma unroll
            for (int kk = 0; kk < 4; kk++)
                A[kk] = *(const bf16x8*)&s_hA[(rt * 16 + m16) * HP + kk * 32 + quad * 8];
            #pragma unroll
            for (int ct = 0; ct < 4; ct++) {
                f32x4 acc = {0.f, 0.f, 0.f, 0.f};
                #pragma unroll
                for (int kk = 0; kk < 4; kk++)
                    acc = __builtin_amdgcn_mfma_f32_16x16x32_bf16(A[kk], B[ct][kk], acc, 0, 0, 0);
                int col = wv * 64 + ct * 16 + m16;
                float bb = b1[col];
                #pragma unroll
                for (int r = 0; r < 4; r++)
                    s_x[(rt * 16 + quad * 4 + r) * XP + col] = f2bf(gelu_f(acc[r] + bb));
            }
        }
    }
    __syncthreads();

    // ---- Phase 4: MFMA GEMM2  h2 = gelu(x @ w2^T + b2), wave strip cols [wv*32, wv*32+32) ----
    {
        bf16x8 B2[2][8];
        #pragma unroll
        for (int ct = 0; ct < 2; ct++)
            #pragma unroll
            for (int kk = 0; kk < 8; kk++)
                B2[ct][kk] = *(const bf16x8*)&w2b[(wv * 32 + ct * 16 + m16) * 256 + kk * 32 + quad * 8];
        #pragma unroll
        for (int rt = 0; rt < 4; rt++) {
            bf16x8 A[8];
            #pragma unroll
            for (int kk = 0; kk < 8; kk++)
                A[kk] = *(const bf16x8*)&s_x[(rt * 16 + m16) * XP + kk * 32 + quad * 8];
            #pragma unroll
            for (int ct = 0; ct < 2; ct++) {
                f32x4 acc = {0.f, 0.f, 0.f, 0.f};
                #pragma unroll
                for (int kk = 0; kk < 8; kk++)
                    acc = __builtin_amdgcn_mfma_f32_16x16x32_bf16(A[kk], B2[ct][kk], acc, 0, 0, 0);
                int col = wv * 32 + ct * 16 + m16;
                float bb = b2[col];
                #pragma unroll
                for (int r = 0; r < 4; r++)
                    s_hA[(rt * 16 + quad * 4 + r) * HP + col] = f2bf(gelu_f(acc[r] + bb));
            }
        }
    }
    __syncthreads();

    // ---- Phase 5: pool mean/max over K=32 per query (h2 in s_hA) ----
    {
        int qi = t >> 7, d = t & 127;
        float sm = 0.f, mx = -INFINITY;
        #pragma unroll
        for (int k = 0; k < KN; k++) {
            float v = bf2f(s_hA[(qi * KN + k) * HP + d]);
            sm += v; mx = fmaxf(mx, v);
        }
        s_pool[qi * 256 + d]       = sm * (1.0f / KN);
        s_pool[qi * 256 + 128 + d] = mx;
    }
    __syncthreads();

    // ---- Phase 6: head LN over 256 (one wave per query) ----
    if (t < 128) {
        int qi = t >> 6, l = t & 63;
        float v0 = s_pool[qi * 256 + l],       v1 = s_pool[qi * 256 + l + 64];
        float v2 = s_pool[qi * 256 + l + 128], v3 = s_pool[qi * 256 + l + 192];
        float s = v0 + v1 + v2 + v3;
        float ss = v0 * v0 + v1 * v1 + v2 * v2 + v3 * v3;
        #pragma unroll
        for (int m = 1; m < 64; m <<= 1) {
            s  += __shfl_xor(s, m);
            ss += __shfl_xor(ss, m);
        }
        float mean = s * (1.0f / (2 * DD));
        float var  = ss * (1.0f / (2 * DD)) - mean * mean;
        float rstd = rsqrtf(fmaxf(var, 0.0f) + 1e-5f);
        s_pln[qi * 256 + l]       = (v0 - mean) * rstd * hln_g[l]       + hln_b[l];
        s_pln[qi * 256 + l + 64]  = (v1 - mean) * rstd * hln_g[l + 64]  + hln_b[l + 64];
        s_pln[qi * 256 + l + 128] = (v2 - mean) * rstd * hln_g[l + 128] + hln_b[l + 128];
        s_pln[qi * 256 + l + 192] = (v3 - mean) * rstd * hln_g[l + 192] + hln_b[l + 192];
    }
    __syncthreads();

    // ---- Phase 7: head MLP, thread t = hidden unit f, both queries ----
    {
        float a0 = hb1[t], a1 = a0;
        #pragma unroll 8
        for (int c2 = 0; c2 < 128; c2++) {
            unsigned v = hw1p[c2 * 256 + t];          // coalesced 4B/lane
            float w0 = bf2f((unsigned short)(v & 0xffffu));
            float w1 = bf2f((unsigned short)(v >> 16));
            float p00 = s_pln[2 * c2], p01 = s_pln[2 * c2 + 1];          // broadcast
            float p10 = s_pln[256 + 2 * c2], p11 = s_pln[256 + 2 * c2 + 1];
            a0 = fmaf(w0, p00, fmaf(w1, p01, a0));
            a1 = fmaf(w0, p10, fmaf(w1, p11, a1));
        }
        float hv = hw2[t];
        float c0 = gelu_f(a0) * hv, c1 = gelu_f(a1) * hv;
        #pragma unroll
        for (int m = 1; m < 64; m <<= 1) {
            c0 += __shfl_xor(c0, m);
            c1 += __shfl_xor(c1, m);
        }
        if (lane == 0) { s_red[wv][0] = c0; s_red[wv][1] = c1; }
    }
    __syncthreads();
    if (t == 0) {
        float u0 = s_red[0][0] + s_red[1][0] + s_red[2][0] + s_red[3][0] + hb2[0];
        float u1 = s_red[0][1] + s_red[1][1] + s_red[2][1] + s_red[3][1] + hb2[0];
        out[q0 + 0] = u0 * s_sig[0] + s_mu[0];
        out[q0 + 1] = u1 * s_sig[1] + s_mu[1];
    }
}

extern "C" void kernel_launch(void* const* d_in, const int* in_sizes, int n_in,
                              void* d_out, int out_size, void* d_ws, size_t ws_size,
                              hipStream_t stream)
{
    const float* xyt_q      = (const float*)d_in[0];
    const float* obs_coords = (const float*)d_in[1];
    const float* obs_vals   = (const float*)d_in[2];
    const int*   nb_idx     = (const int*)d_in[3];
    const float* log_gammas = (const float*)d_in[4];
    const float* w_in  = (const float*)d_in[5];
    const float* b_in  = (const float*)d_in[6];
    const float* ln1_g = (const float*)d_in[7];
    const float* ln1_b = (const float*)d_in[8];
    const float* w1    = (const float*)d_in[9];
    const float* b1    = (const float*)d_in[10];
    const float* w2    = (const float*)d_in[11];
    const float* b2    = (const float*)d_in[12];
    const float* hln_g = (const float*)d_in[13];
    const float* hln_b = (const float*)d_in[14];
    const float* hw1   = (const float*)d_in[15];
    const float* hb1   = (const float*)d_in[16];
    const float* hw2   = (const float*)d_in[17];
    const float* hb2   = (const float*)d_in[18];
    float* out = (float*)d_out;

    const int Q = in_sizes[0] / 3;   // 32768

    // d_ws layout: w1b bf16 (64 KB) | w2b bf16 (64 KB) | hw1p packed (128 KB)
    unsigned short* w1b  = (unsigned short*)d_ws;
    unsigned short* w2b  = w1b + 32768;
    unsigned*       hw1p = (unsigned*)((char*)d_ws + 131072);

    prep_kernel<<<128, 256, 0, stream>>>(w1, w2, hw1, w1b, w2b, hw1p);

    ff_mfma_kernel<<<Q / QB, 256, 0, stream>>>(
        xyt_q, obs_coords, obs_vals, nb_idx, log_gammas,
        w_in, b_in, ln1_g, ln1_b,
        w1b, b1, w2b, b2,
        hln_g, hln_b, hw1p, hb1, hw2, hb2, out);
}

// Round 3
// 727.064 us; speedup vs baseline: 6.4714x; 1.1763x over previous
//
#include <hip/hip_runtime.h>
#include <math.h>

// FieldFormer fused kernel, round 3: same structure as round 2, but GELU via
// Abramowitz-Stegun 7.1.26 erf (max abs err 1.5e-7, ~46 cyc) instead of libm
// erff (~200 cyc, branchless dual-path). 130 gelu/thread/block made erff ~78%
// of VALU issue in round 2.
#define KN 32
#define DD 128
#define FF 256
#define QB 2
#define MROWS (QB * KN)      // 64
#define HP 136               // s_hA pitch (ushort), 128+8 pad
#define XP 264               // s_x  pitch (ushort), 256+8 pad

typedef __attribute__((ext_vector_type(8))) short bf16x8;
typedef __attribute__((ext_vector_type(4))) float f32x4;

__device__ __forceinline__ unsigned short f2bf(float x) {
    union { float f; unsigned u; } c; c.f = x;
    unsigned r = c.u + 0x7fffu + ((c.u >> 16) & 1u);   // RNE
    return (unsigned short)(r >> 16);
}
__device__ __forceinline__ float bf2f(unsigned short h) {
    union { unsigned u; float f; } c; c.u = ((unsigned)h) << 16;
    return c.f;
}

// gelu(x) = 0.5*x*(1+erf(x/sqrt2)), erf via A&S 7.1.26 (|err|<=1.5e-7).
// z = |x|/sqrt2; t = 1/(1+0.3275911 z); erf = 1 - poly(t)*exp(-z^2).
__device__ __forceinline__ float gelu_f(float x) {
    float z  = __builtin_fabsf(x) * 0.70710678118654752440f;
    float z2 = z * z;
    float e  = __builtin_amdgcn_exp2f(z2 * -1.4426950408889634f);   // exp(-z^2)
    float t  = __builtin_amdgcn_rcpf(fmaf(0.3275911f, z, 1.0f));
    float p  = fmaf(1.061405429f, t, -1.453152027f);
    p = fmaf(p, t, 1.421413741f);
    p = fmaf(p, t, -0.284496736f);
    p = fmaf(p, t, 0.254829592f);
    p = p * t;
    float erfz = fmaf(-p, e, 1.0f);                 // erf(|x|/sqrt2)
    float erfs = (x < 0.0f) ? -erfz : erfz;
    float hx = 0.5f * x;
    return fmaf(hx, erfs, hx);
}

// Prep: w1 [256,128] -> bf16, w2 [128,256] -> bf16, hw1 [256,256] -> transposed
// packed pairs hw1p[c2*256+f] = (bf16(hw1[f][2c2]), bf16(hw1[f][2c2+1])).
__global__ void prep_kernel(const float* __restrict__ w1,
                            const float* __restrict__ w2,
                            const float* __restrict__ hw1,
                            unsigned short* __restrict__ w1b,
                            unsigned short* __restrict__ w2b,
                            unsigned* __restrict__ hw1p) {
    int i = blockIdx.x * 256 + threadIdx.x;   // 0..32767
    w1b[i] = f2bf(w1[i]);
    w2b[i] = f2bf(w2[i]);
    int c2 = i >> 8, f = i & 255;
    unsigned lo = f2bf(hw1[f * 256 + 2 * c2]);
    unsigned hi = f2bf(hw1[f * 256 + 2 * c2 + 1]);
    hw1p[i] = lo | (hi << 16);
}

__launch_bounds__(256, 3)
__global__ void ff_mfma_kernel(
    const float* __restrict__ xyt_q,
    const float* __restrict__ obs_coords,
    const float* __restrict__ obs_vals,
    const int*   __restrict__ nb_idx,
    const float* __restrict__ log_gammas,
    const float* __restrict__ w_in,   // [128,4]
    const float* __restrict__ b_in,
    const float* __restrict__ ln1_g,
    const float* __restrict__ ln1_b,
    const unsigned short* __restrict__ w1b,  // [256,128] bf16
    const float* __restrict__ b1,
    const unsigned short* __restrict__ w2b,  // [128,256] bf16
    const float* __restrict__ b2,
    const float* __restrict__ hln_g,
    const float* __restrict__ hln_b,
    const unsigned* __restrict__ hw1p,       // [128,256] packed bf16 pairs
    const float* __restrict__ hb1,
    const float* __restrict__ hw2,
    const float* __restrict__ hb2,
    float* __restrict__ out)
{
    __shared__ __align__(16) unsigned short s_hA[MROWS * HP];  // 17408 B: h_ln, then h2
    __shared__ __align__(16) unsigned char  s_big[33792];      // aliased: hf fp32 / x bf16 / pool+pln
    __shared__ __align__(16) float s_tokf[MROWS][4];
    __shared__ float s_mu[QB], s_sig[QB];
    __shared__ float s_red[4][QB];

    const int t    = threadIdx.x;
    const int lane = t & 63;
    const int wv   = t >> 6;
    const int m16  = lane & 15;
    const int quad = lane >> 4;
    const int q0   = blockIdx.x * QB;

    float*          hf     = (float*)s_big;            // [64][132] fp32 (phase 1-2)
    unsigned short* s_x    = (unsigned short*)s_big;   // [64][264] bf16 (phase 3-4)
    float*          s_pool = (float*)s_big;            // [2][256]  (phase 5-6)
    float*          s_pln  = (float*)(s_big + 4096);   // [2][256]

    // ---- Phase 0: gather neighbors, tokens, mu/sigma (ddof=1, clip 1e-3) ----
    if (t < MROWS) {
        int qi = t >> 5, j = t & 31;
        int q = q0 + qi;
        int idx = nb_idx[q * KN + j];
        float v = obs_vals[idx];
        float g0 = expf(log_gammas[0]), g1 = expf(log_gammas[1]), g2 = expf(log_gammas[2]);
        s_tokf[t][0] = (obs_coords[idx * 3 + 0] - xyt_q[q * 3 + 0]) * g0;
        s_tokf[t][1] = (obs_coords[idx * 3 + 1] - xyt_q[q * 3 + 1]) * g1;
        s_tokf[t][2] = (obs_coords[idx * 3 + 2] - xyt_q[q * 3 + 2]) * g2;
        float s = v, ss = v * v;
        #pragma unroll
        for (int m = 1; m < 32; m <<= 1) {
            s  += __shfl_xor(s, m);
            ss += __shfl_xor(ss, m);
        }
        float mu  = s * (1.0f / KN);
        float var = (ss - (float)KN * mu * mu) * (1.0f / (KN - 1));
        float sig = fmaxf(sqrtf(fmaxf(var, 0.0f)), 1e-3f);
        if (j == 0) { s_mu[qi] = mu; s_sig[qi] = sig; }
        s_tokf[t][3] = (v - mu) / sig;
    }
    __syncthreads();

    // ---- Phase 1: hf = gelu(tok @ w_in^T + b_in)  [64,128] fp32 ----
    #pragma unroll
    for (int i = 0; i < 32; i++) {
        int idx = t + 256 * i;         // 0..8191
        int tok = idx >> 7, d = idx & 127;
        float4 w  = ((const float4*)w_in)[d];
        float4 tk = *(const float4*)&s_tokf[tok][0];
        float a = fmaf(w.x, tk.x, fmaf(w.y, tk.y, fmaf(w.z, tk.z, fmaf(w.w, tk.w, b_in[d]))));
        hf[tok * 132 + d] = gelu_f(a);
    }
    __syncthreads();

    // ---- Phase 2: LN over 128 (fp32) -> bf16 s_hA ----
    {
        float g0 = ln1_g[lane], g1 = ln1_g[lane + 64];
        float c0 = ln1_b[lane], c1 = ln1_b[lane + 64];
        #pragma unroll
        for (int i = 0; i < 16; i++) {
            int tok = wv * 16 + i;
            float v0 = hf[tok * 132 + lane], v1 = hf[tok * 132 + 64 + lane];
            float s = v0 + v1, ss = v0 * v0 + v1 * v1;
            #pragma unroll
            for (int m = 1; m < 64; m <<= 1) {
                s  += __shfl_xor(s, m);
                ss += __shfl_xor(ss, m);
            }
            float mean = s * (1.0f / DD);
            float var  = ss * (1.0f / DD) - mean * mean;
            float rstd = rsqrtf(fmaxf(var, 0.0f) + 1e-5f);
            s_hA[tok * HP + lane]      = f2bf((v0 - mean) * rstd * g0 + c0);
            s_hA[tok * HP + 64 + lane] = f2bf((v1 - mean) * rstd * g1 + c1);
        }
    }
    __syncthreads();

    // ---- Phase 3: MFMA GEMM1  x = gelu(hln @ w1^T + b1), wave strip cols [wv*64, wv*64+64) ----
    {
        bf16x8 B[4][4];
        #pragma unroll
        for (int ct = 0; ct < 4; ct++)
            #pragma unroll
            for (int kk = 0; kk < 4; kk++)
                B[ct][kk] = *(const bf16x8*)&w1b[(wv * 64 + ct * 16 + m16) * 128 + kk * 32 + quad * 8];
        #pragma unroll
        for (int rt = 0; rt < 4; rt++) {
            bf16x8 A[4];
            #pragma unroll
            for (int kk = 0; kk < 4; kk++)
                A[kk] = *(const bf16x8*)&s_hA[(rt * 16 + m16) * HP + kk * 32 + quad * 8];
            #pragma unroll
            for (int ct = 0; ct < 4; ct++) {
                f32x4 acc = {0.f, 0.f, 0.f, 0.f};
                #pragma unroll
                for (int kk = 0; kk < 4; kk++)
                    acc = __builtin_amdgcn_mfma_f32_16x16x32_bf16(A[kk], B[ct][kk], acc, 0, 0, 0);
                int col = wv * 64 + ct * 16 + m16;
                float bb = b1[col];
                #pragma unroll
                for (int r = 0; r < 4; r++)
                    s_x[(rt * 16 + quad * 4 + r) * XP + col] = f2bf(gelu_f(acc[r] + bb));
            }
        }
    }
    __syncthreads();

    // ---- Phase 4: MFMA GEMM2  h2 = gelu(x @ w2^T + b2), wave strip cols [wv*32, wv*32+32) ----
    {
        bf16x8 B2[2][8];
        #pragma unroll
        for (int ct = 0; ct < 2; ct++)
            #pragma unroll
            for (int kk = 0; kk < 8; kk++)
                B2[ct][kk] = *(const bf16x8*)&w2b[(wv * 32 + ct * 16 + m16) * 256 + kk * 32 + quad * 8];
        #pragma unroll
        for (int rt = 0; rt < 4; rt++) {
            bf16x8 A[8];
            #pragma unroll
            for (int kk = 0; kk < 8; kk++)
                A[kk] = *(const bf16x8*)&s_x[(rt * 16 + m16) * XP + kk * 32 + quad * 8];
            #pragma unroll
            for (int ct = 0; ct < 2; ct++) {
                f32x4 acc = {0.f, 0.f, 0.f, 0.f};
                #pragma unroll
                for (int kk = 0; kk < 8; kk++)
                    acc = __builtin_amdgcn_mfma_f32_16x16x32_bf16(A[kk], B2[ct][kk], acc, 0, 0, 0);
                int col = wv * 32 + ct * 16 + m16;
                float bb = b2[col];
                #pragma unroll
                for (int r = 0; r < 4; r++)
                    s_hA[(rt * 16 + quad * 4 + r) * HP + col] = f2bf(gelu_f(acc[r] + bb));
            }
        }
    }
    __syncthreads();

    // ---- Phase 5: pool mean/max over K=32 per query (h2 in s_hA) ----
    {
        int qi = t >> 7, d = t & 127;
        float sm = 0.f, mx = -INFINITY;
        #pragma unroll
        for (int k = 0; k < KN; k++) {
            float v = bf2f(s_hA[(qi * KN + k) * HP + d]);
            sm += v; mx = fmaxf(mx, v);
        }
        s_pool[qi * 256 + d]       = sm * (1.0f / KN);
        s_pool[qi * 256 + 128 + d] = mx;
    }
    __syncthreads();

    // ---- Phase 6: head LN over 256 (one wave per query) ----
    if (t < 128) {
        int qi = t >> 6, l = t & 63;
        float v0 = s_pool[qi * 256 + l],       v1 = s_pool[qi * 256 + l + 64];
        float v2 = s_pool[qi * 256 + l + 128], v3 = s_pool[qi * 256 + l + 192];
        float s = v0 + v1 + v2 + v3;
        float ss = v0 * v0 + v1 * v1 + v2 * v2 + v3 * v3;
        #pragma unroll
        for (int m = 1; m < 64; m <<= 1) {
            s  += __shfl_xor(s, m);
            ss += __shfl_xor(ss, m);
        }
        float mean = s * (1.0f / (2 * DD));
        float var  = ss * (1.0f / (2 * DD)) - mean * mean;
        float rstd = rsqrtf(fmaxf(var, 0.0f) + 1e-5f);
        s_pln[qi * 256 + l]       = (v0 - mean) * rstd * hln_g[l]       + hln_b[l];
        s_pln[qi * 256 + l + 64]  = (v1 - mean) * rstd * hln_g[l + 64]  + hln_b[l + 64];
        s_pln[qi * 256 + l + 128] = (v2 - mean) * rstd * hln_g[l + 128] + hln_b[l + 128];
        s_pln[qi * 256 + l + 192] = (v3 - mean) * rstd * hln_g[l + 192] + hln_b[l + 192];
    }
    __syncthreads();

    // ---- Phase 7: head MLP, thread t = hidden unit f, both queries ----
    {
        float a0 = hb1[t], a1 = a0;
        #pragma unroll 8
        for (int c2 = 0; c2 < 128; c2++) {
            unsigned v = hw1p[c2 * 256 + t];          // coalesced 4B/lane
            float w0 = bf2f((unsigned short)(v & 0xffffu));
            float w1 = bf2f((unsigned short)(v >> 16));
            float p00 = s_pln[2 * c2], p01 = s_pln[2 * c2 + 1];
            float p10 = s_pln[256 + 2 * c2], p11 = s_pln[256 + 2 * c2 + 1];
            a0 = fmaf(w0, p00, fmaf(w1, p01, a0));
            a1 = fmaf(w0, p10, fmaf(w1, p11, a1));
        }
        float hv = hw2[t];
        float c0 = gelu_f(a0) * hv, c1 = gelu_f(a1) * hv;
        #pragma unroll
        for (int m = 1; m < 64; m <<= 1) {
            c0 += __shfl_xor(c0, m);
            c1 += __shfl_xor(c1, m);
        }
        if (lane == 0) { s_red[wv][0] = c0; s_red[wv][1] = c1; }
    }
    __syncthreads();
    if (t == 0) {
        float u0 = s_red[0][0] + s_red[1][0] + s_red[2][0] + s_red[3][0] + hb2[0];
        float u1 = s_red[0][1] + s_red[1][1] + s_red[2][1] + s_red[3][1] + hb2[0];
        out[q0 + 0] = u0 * s_sig[0] + s_mu[0];
        out[q0 + 1] = u1 * s_sig[1] + s_mu[1];
    }
}

extern "C" void kernel_launch(void* const* d_in, const int* in_sizes, int n_in,
                              void* d_out, int out_size, void* d_ws, size_t ws_size,
                              hipStream_t stream)
{
    const float* xyt_q      = (const float*)d_in[0];
    const float* obs_coords = (const float*)d_in[1];
    const float* obs_vals   = (const float*)d_in[2];
    const int*   nb_idx     = (const int*)d_in[3];
    const float* log_gammas = (const float*)d_in[4];
    const float* w_in  = (const float*)d_in[5];
    const float* b_in  = (const float*)d_in[6];
    const float* ln1_g = (const float*)d_in[7];
    const float* ln1_b = (const float*)d_in[8];
    const float* w1    = (const float*)d_in[9];
    const float* b1    = (const float*)d_in[10];
    const float* w2    = (const float*)d_in[11];
    const float* b2    = (const float*)d_in[12];
    const float* hln_g = (const float*)d_in[13];
    const float* hln_b = (const float*)d_in[14];
    const float* hw1   = (const float*)d_in[15];
    const float* hb1   = (const float*)d_in[16];
    const float* hw2   = (const float*)d_in[17];
    const float* hb2   = (const float*)d_in[18];
    float* out = (float*)d_out;

    const int Q = in_sizes[0] / 3;   // 32768

    unsigned short* w1b  = (unsigned short*)d_ws;
    unsigned short* w2b  = w1b + 32768;
    unsigned*       hw1p = (unsigned*)((char*)d_ws + 131072);

    prep_kernel<<<128, 256, 0, stream>>>(w1, w2, hw1, w1b, w2b, hw1p);

    ff_mfma_kernel<<<Q / QB, 256, 0, stream>>>(
        xyt_q, obs_coords, obs_vals, nb_idx, log_gammas,
        w_in, b_in, ln1_g, ln1_b,
        w1b, b1, w2b, b2,
        hln_g, hln_b, hw1p, hb1, hw2, hb2, out);
}